// Round 6
// baseline (183.101 us; speedup 1.0000x reference)
//
#include <hip/hip_runtime.h>
#include <hip/hip_bf16.h>

// Problem constants (from setup_inputs)
#define Bb 8
#define Tt 20
#define Nn 16
#define Cc 1024
#define ROWS (Bb * Tt * Nn)   // 2560
#define K2 9

typedef __attribute__((ext_vector_type(8))) short short8;
typedef __attribute__((ext_vector_type(8))) _Float16 half8;
typedef __attribute__((ext_vector_type(4))) _Float16 half4;
typedef __attribute__((ext_vector_type(4))) float floatx4;
typedef __attribute__((address_space(1))) const unsigned int guint;
typedef __attribute__((address_space(3))) unsigned int luint;

static __device__ __forceinline__ unsigned short f2bf(float f) {
    unsigned int u = __builtin_bit_cast(unsigned int, f);
    unsigned int lsb = (u >> 16) & 1u;
    u += 0x7fffu + lsb;                 // round-to-nearest-even
    return (unsigned short)(u >> 16);
}

// ---------------------------------------------------------------------------
// Kernel 0 (prep): one kernel, five block-segments.
//   [0,1024)      : W_hidden fp32 -> bf16 (4 elem/thread)
//   [1024,3584)   : x fp32 -> fp16        (4 elem/thread)
//   [3584,4736)   : conv weights -> [tap][32][C] fp16 (o zero-padded to 32)
//   [4736,4916)   : off1/off2 bias init (offs kernel atomicAdds partials)
//   [4916,7476)   : dyn zero-init (gemm split-K atomicAdds partials)
// ---------------------------------------------------------------------------
#define SEG0 1024
#define SEG1 3584
#define SEG2 4736
#define SEG3 4916
#define SEG4 7476

__global__ __launch_bounds__(256) void prep_kernel(const float* __restrict__ pf,
                                                   const float* __restrict__ Wh,
                                                   const float* __restrict__ w1,
                                                   const float* __restrict__ b1,
                                                   const float* __restrict__ w2,
                                                   const float* __restrict__ b2,
                                                   unsigned short* __restrict__ Wb,
                                                   _Float16* __restrict__ xh,
                                                   _Float16* __restrict__ wh1,
                                                   _Float16* __restrict__ wh2,
                                                   float* __restrict__ off1,
                                                   float* __restrict__ off2,
                                                   float* __restrict__ dyn) {
    const int bid = blockIdx.x;
    const int tid = threadIdx.x;
    if (bid < SEG0) {
        int idx = (bid * 256 + tid) * 4;
        float4 v = *(const float4*)(Wh + idx);
        ushort4 o;
        o.x = f2bf(v.x); o.y = f2bf(v.y); o.z = f2bf(v.z); o.w = f2bf(v.w);
        *(ushort4*)(Wb + idx) = o;
    } else if (bid < SEG1) {
        int idx = ((bid - SEG0) * 256 + tid) * 4;
        float4 v = *(const float4*)(pf + idx);
        half4 o;
        o.x = (_Float16)v.x; o.y = (_Float16)v.y; o.z = (_Float16)v.z; o.w = (_Float16)v.w;
        *(half4*)(xh + idx) = o;
    } else if (bid < SEG2) {
        int idx = (bid - SEG1) * 256 + tid;     // 9*32*1024 total
        int c = idx & 1023;
        int o = (idx >> 10) & 31;
        int tap = idx >> 15;
        float v1 = 0.f, v2 = 0.f;
        if (o < 18) {
            size_t src = ((size_t)o * Cc + c) * 9 + tap;
            v1 = w1[src]; v2 = w2[src];
        }
        wh1[idx] = (_Float16)v1;
        wh2[idx] = (_Float16)v2;
    } else if (bid < SEG3) {
        int idx = (bid - SEG2) * 256 + tid;     // ROWS*18 = 46080 = 180*256
        int o = idx % 18;
        off1[idx] = b1[o];
        off2[idx] = b2[o];
    } else {
        int idx = ((bid - SEG3) * 256 + tid) * 4;   // 2560*1024 floats exactly
        *(float4*)(dyn + idx) = (float4){0.f, 0.f, 0.f, 0.f};
    }
}

// ---------------------------------------------------------------------------
// Kernel 1: offset conv, ALL 9 taps per block, K-SPLIT for parallelism.
// Grid (40 M-tiles of 64 rows, 8 K-chunks of 128, 2 ratios) = 640 blocks
// (R4 known-good config — unchanged).
// ---------------------------------------------------------------------------
__global__ __launch_bounds__(256) void offs_mfma_kernel(const _Float16* __restrict__ xh,
                                                        const _Float16* __restrict__ wh1,
                                                        const _Float16* __restrict__ wh2,
                                                        float* __restrict__ off1,
                                                        float* __restrict__ off2) {
    __shared__ unsigned short As[2][146 * 32];      // 2 x 9.1 KB (144 win + zero + pad)
    __shared__ unsigned short Bs[2][9 * 32 * 32];   // 2 x 18 KB

    const int tid  = threadIdx.x;
    const int lane = tid & 63;
    const int wave = tid >> 6;
    const int quad = lane >> 4;
    const int l15  = lane & 15;
    const int row0 = blockIdx.x * 64;               // 64 | 320: never crosses a batch
    const int kc   = blockIdx.y * 128;              // this block's K range: [kc, kc+128)
    const int ratio = blockIdx.z + 1;
    const _Float16* __restrict__ wh = blockIdx.z ? wh2 : wh1;
    float* __restrict__ off         = blockIdx.z ? off2 : off1;

    const int wrow = wave * 16;                     // this wave's 16 rows = one t-slice
    const int t_w  = ((row0 + wrow) >> 4) % Tt;

    unsigned bOffs[5], aOffs[3];
#pragma unroll
    for (int i = 0; i < 5; ++i) {
        const int c = (wave + i * 4) * 64 + lane;
        const int tap = c >> 7, rem = c & 127, o = rem >> 2, p = rem & 3;
        bOffs[i] = tap * 32768 + o * 1024 + ((p ^ (o & 3)) << 3);
    }
#pragma unroll
    for (int i = 0; i < 3; ++i) {
        const int c = (wave + i * 4) * 64 + lane;
        const int r = c >> 2, p = c & 3;
        int gr = row0 - 40 + r;                     // clamp for safety; invalid rows
        gr = gr < 0 ? 0 : (gr > ROWS - 1 ? ROWS - 1 : gr);  // are masked by validity
        aOffs[i] = (unsigned)gr * 1024 + ((p ^ (r & 3)) << 3);
    }

    auto stage = [&](int buf, int kt) {
#pragma unroll
        for (int i = 0; i < 5; ++i) {
            const int g = wave + i * 4;
            if (g < 18)
                __builtin_amdgcn_global_load_lds((guint*)(const void*)(wh + bOffs[i] + kt),
                                                 (luint*)(void*)&Bs[buf][g * 512], 16, 0, 0);
        }
#pragma unroll
        for (int i = 0; i < 3; ++i) {
            const int g = wave + i * 4;
            if (g < 9)
                __builtin_amdgcn_global_load_lds((guint*)(const void*)(xh + aOffs[i] + kt),
                                                 (luint*)(void*)&As[buf][g * 512], 16, 0, 0);
        }
    };

    int addrA[9];
#pragma unroll
    for (int tap = 0; tap < 9; ++tap) {
        const int dt = (tap / 3 - 1) * ratio;
        const int dn = (tap % 3 - 1) * ratio;
        const bool tv = (unsigned)(t_w + dt) < (unsigned)Tt;   // wave-uniform
        const bool nv = (unsigned)(l15 + dn) < (unsigned)Nn;   // per-lane
        const int r  = wrow + l15 + 40 + dt * 16 + dn;         // window row
        const int rr = (tv && nv) ? r : 144;                   // else zero row
        addrA[tap] = rr * 32 + ((quad ^ (rr & 3)) << 3);
    }
    const int bOff0 = l15 * 32 + ((quad ^ (l15 & 3)) << 3);

    if (tid < 8) {
        short8 z = {0, 0, 0, 0, 0, 0, 0, 0};
        *(short8*)&As[tid >> 2][144 * 32 + (tid & 3) * 8] = z;
    }

    floatx4 acc[2];
    acc[0] = (floatx4){0.f, 0.f, 0.f, 0.f};
    acc[1] = (floatx4){0.f, 0.f, 0.f, 0.f};

    stage(0, kc);
    __syncthreads();
    int cur = 0;
#pragma unroll
    for (int ks = 0; ks < 4; ++ks) {                // 4 K-steps of 32
        const bool more = (ks < 3);
        if (more) stage(cur ^ 1, kc + (ks + 1) * 32);   // prefetch under the MFMAs
#pragma unroll
        for (int tap = 0; tap < 9; ++tap) {
            const half8 av  = __builtin_bit_cast(half8, *(const short8*)&As[cur][addrA[tap]]);
            const half8 bv0 = __builtin_bit_cast(half8, *(const short8*)&Bs[cur][tap * 1024 + bOff0]);
            const half8 bv1 = __builtin_bit_cast(half8, *(const short8*)&Bs[cur][tap * 1024 + 512 + bOff0]);
            acc[0] = __builtin_amdgcn_mfma_f32_16x16x32_f16(av, bv0, acc[0], 0, 0, 0);
            acc[1] = __builtin_amdgcn_mfma_f32_16x16x32_f16(av, bv1, acc[1], 0, 0, 0);
        }
        if (more) __syncthreads();                  // single drain point per K-step
        cur ^= 1;
    }

#pragma unroll
    for (int j = 0; j < 2; ++j) {
        const int o = j * 16 + l15;
        if (o < 18) {
            const int grow = row0 + wrow + quad * 4;
#pragma unroll
            for (int r = 0; r < 4; ++r)
                atomicAdd(&off[(size_t)(grow + r) * 18 + o], acc[j][r]);
        }
    }
}

// ---------------------------------------------------------------------------
// Kernel 2: fused deformable bilinear gather, descriptor form (R1/R4 known-
// good config — unchanged).
// ---------------------------------------------------------------------------
__global__ __launch_bounds__(256) void gather_kernel(const float* __restrict__ pf,
                                                     const float* __restrict__ off1,
                                                     const float* __restrict__ off2,
                                                     unsigned short* __restrict__ Ab,
                                                     float* __restrict__ mad) {
    const int bid = blockIdx.x;
    const int row = (bid & 7) * (ROWS / 8) + (bid >> 3);   // bijective XCD swizzle
    const int b = row / (Tt * Nn);
    const int t = (row / Nn) % Tt;
    const int n = row % Nn;
    const int tid = threadIdx.x;

    __shared__ float4 scoef[18];
    __shared__ int4   soffs[18];

    if (tid < 18) {
        const int ratio = (tid < 9) ? 1 : 2;
        const int k = (tid < 9) ? tid : tid - 9;
        const float* offarr = (tid < 9) ? off1 : off2;
        const float ot = offarr[(size_t)row * 18 + k];
        const float on = offarr[(size_t)row * 18 + 9 + k];
        const float tmax = (float)(Tt + 2 * ratio - 1);
        const float nmax = (float)(Nn + 2 * ratio - 1);
        const float pos_t = (float)(t + ratio + (k / 3 - 1) * ratio) + ot;
        const float pos_n = (float)(n + ratio + (k % 3 - 1) * ratio) + on;

        const float fl_t = floorf(pos_t), fl_n = floorf(pos_n);
        const float l_t = fminf(fmaxf(fl_t, 0.f), tmax);
        const float r_t = fminf(fmaxf(fl_t + 1.f, 0.f), tmax);
        const float l_n = fminf(fmaxf(fl_n, 0.f), nmax);
        const float r_n = fminf(fmaxf(fl_n + 1.f, 0.f), nmax);
        const float pt_ = fminf(fmaxf(pos_t, 0.f), tmax);
        const float pn_ = fminf(fmaxf(pos_n, 0.f), nmax);

        const float wtl = 1.f - fabsf(pt_ - l_t);
        const float wtr = 1.f - fabsf(pt_ - r_t);
        const float wnl = 1.f - fabsf(pn_ - l_n);
        const float wnr = 1.f - fabsf(pn_ - r_n);

        const int ilt = (int)l_t - ratio, irt = (int)r_t - ratio;
        const int iln = (int)l_n - ratio, irn = (int)r_n - ratio;
        const bool vtl = (unsigned)ilt < (unsigned)Tt;
        const bool vtr = (unsigned)irt < (unsigned)Tt;
        const bool vnl = (unsigned)iln < (unsigned)Nn;
        const bool vnr = (unsigned)irn < (unsigned)Nn;

        const int bb = b * Tt;
        float4 cf;
        int4 of;
        const bool g0 = vtl && vnl, g1 = vtr && vnr, g2 = vtr && vnl, g3 = vtl && vnr;
        cf.x = g0 ? wtl * wnl : 0.f;
        cf.y = g1 ? wtr * wnr : 0.f;
        cf.z = g2 ? wtr * wnl : 0.f;
        cf.w = g3 ? wtl * wnr : 0.f;
        of.x = g0 ? ((bb + ilt) * Nn + iln) * Cc : 0;
        of.y = g1 ? ((bb + irt) * Nn + irn) * Cc : 0;
        of.z = g2 ? ((bb + irt) * Nn + iln) * Cc : 0;
        of.w = g3 ? ((bb + ilt) * Nn + irn) * Cc : 0;
        scoef[tid] = cf;
        soffs[tid] = of;
    }
    __syncthreads();

    const int c4 = tid * 4;
    float ax = 0.f, ay = 0.f, az = 0.f, aw = 0.f;

#pragma unroll
    for (int d = 0; d < 9; ++d) {
        const float4 cf = scoef[d];
        const int4 of = soffs[d];
        const float4 v0 = *(const float4*)(pf + of.x + c4);
        const float4 v1 = *(const float4*)(pf + of.y + c4);
        const float4 v2 = *(const float4*)(pf + of.z + c4);
        const float4 v3 = *(const float4*)(pf + of.w + c4);
        ax += cf.x * v0.x + cf.y * v1.x + cf.z * v2.x + cf.w * v3.x;
        ay += cf.x * v0.y + cf.y * v1.y + cf.z * v2.y + cf.w * v3.y;
        az += cf.x * v0.z + cf.y * v1.z + cf.z * v2.z + cf.w * v3.z;
        aw += cf.x * v0.w + cf.y * v1.w + cf.z * v2.w + cf.w * v3.w;
    }
#pragma unroll
    for (int d = 9; d < 18; ++d) {
        const float4 cf = scoef[d];
        const int4 of = soffs[d];
        const float4 v0 = *(const float4*)(pf + of.x + c4);
        const float4 v1 = *(const float4*)(pf + of.y + c4);
        const float4 v2 = *(const float4*)(pf + of.z + c4);
        const float4 v3 = *(const float4*)(pf + of.w + c4);
        floatx4 val;
        val.x = cf.x * v0.x + cf.y * v1.x + cf.z * v2.x + cf.w * v3.x;
        val.y = cf.x * v0.y + cf.y * v1.y + cf.z * v2.y + cf.w * v3.y;
        val.z = cf.x * v0.z + cf.y * v1.z + cf.z * v2.z + cf.w * v3.z;
        val.w = cf.x * v0.w + cf.y * v1.w + cf.z * v2.w + cf.w * v3.w;
        __builtin_nontemporal_store(val,
            (floatx4*)(mad + ((size_t)row * 9 + (d - 9)) * Cc + c4));
        ax += val.x; ay += val.y; az += val.z; aw += val.w;
    }

    ushort4 o;
    o.x = f2bf(ax * (1.f / 18.f));
    o.y = f2bf(ay * (1.f / 18.f));
    o.z = f2bf(az * (1.f / 18.f));
    o.w = f2bf(aw * (1.f / 18.f));
    *(ushort4*)(Ab + (size_t)row * Cc + c4) = o;
}

// ---------------------------------------------------------------------------
// Kernel 3: bf16 MFMA GEMM with SPLIT-K=2, 128x64 tiles.
// Grid (20, 16, 2) = 640 blocks (R2's denser tile — 16 MFMA : 12 ds_read
// per wave per K-step — at R4's parallelism; R2's regression was the
// 320-block grid, not the tile). Each block does K=512 (8 K-steps, BK=64
// double-buffered, one barrier per step) and atomicAdds its partial into
// zero-initialized dyn (5.2M fp32 atomics ~ 21 MB RMW, TCC-spread).
// ---------------------------------------------------------------------------
__global__ __launch_bounds__(256) void gemm_bt_kernel(const unsigned short* __restrict__ A,
                                                      const unsigned short* __restrict__ Bw,
                                                      float* __restrict__ C,
                                                      int M, int N, int K) {
    __shared__ unsigned short As[2][128 * 64];  // 2 x 16 KB
    __shared__ unsigned short Bs[2][64 * 64];   // 2 x 8 KB

    const int tid  = threadIdx.x;
    const int lane = tid & 63;
    const int wave = tid >> 6;
    const int quad = lane >> 4;
    const int l15  = lane & 15;
    const int row0 = blockIdx.x * 128;
    const int col0 = blockIdx.y * 64;
    const int kh   = blockIdx.z * 512;          // this block's K half
    const int wm = (wave >> 1) * 64;            // wave row base within tile
    const int wn = (wave & 1) * 32;             // wave col base within tile

    floatx4 acc[4][2];
#pragma unroll
    for (int i = 0; i < 4; ++i)
#pragma unroll
        for (int j = 0; j < 2; ++j) acc[i][j] = (floatx4){0.f, 0.f, 0.f, 0.f};

    // staging map: chunk c = (m = c>>3, p = c&7) holds global k-chunk p^(m&7).
    // A: 1024 chunks (4/thread); B: 512 chunks (2/thread).
    auto srcA = [&](int c) {
        const int m = c >> 3, kq = (c & 7) ^ (m & 7);
        return A + (size_t)(row0 + m) * K + kq * 8;
    };
    auto srcB = [&](int c) {
        const int m = c >> 3, kq = (c & 7) ^ (m & 7);
        return Bw + (size_t)(col0 + m) * K + kq * 8;
    };
    const unsigned short* gA0 = srcA(tid);
    const unsigned short* gA1 = srcA(tid + 256);
    const unsigned short* gA2 = srcA(tid + 512);
    const unsigned short* gA3 = srcA(tid + 768);
    const unsigned short* gB0 = srcB(tid);
    const unsigned short* gB1 = srcB(tid + 256);

    auto stage = [&](int buf, int kt) {
        unsigned short* a  = &As[buf][0] + wave * 512;
        unsigned short* bb = &Bs[buf][0] + wave * 512;
        __builtin_amdgcn_global_load_lds((guint*)(const void*)(gA0 + kt),
                                         (luint*)(void*)a, 16, 0, 0);
        __builtin_amdgcn_global_load_lds((guint*)(const void*)(gA1 + kt),
                                         (luint*)(void*)(a + 2048), 16, 0, 0);
        __builtin_amdgcn_global_load_lds((guint*)(const void*)(gA2 + kt),
                                         (luint*)(void*)(a + 4096), 16, 0, 0);
        __builtin_amdgcn_global_load_lds((guint*)(const void*)(gA3 + kt),
                                         (luint*)(void*)(a + 6144), 16, 0, 0);
        __builtin_amdgcn_global_load_lds((guint*)(const void*)(gB0 + kt),
                                         (luint*)(void*)bb, 16, 0, 0);
        __builtin_amdgcn_global_load_lds((guint*)(const void*)(gB1 + kt),
                                         (luint*)(void*)(bb + 2048), 16, 0, 0);
    };

    stage(0, kh);
    __syncthreads();
    int cur = 0;
    for (int kt = kh; kt < kh + 512; kt += 64) {
        const bool more = (kt + 64 < kh + 512);
        if (more) stage(cur ^ 1, kt + 64);   // prefetch under the MFMAs

#pragma unroll
        for (int kt2 = 0; kt2 < 2; ++kt2) {
            short8 af[4], bf[2];
#pragma unroll
            for (int i = 0; i < 4; ++i) {
                const int mm = wm + i * 16 + l15;
                af[i] = *(const short8*)&As[cur][mm * 64 + (((kt2 * 4 + quad) ^ (mm & 7)) << 3)];
            }
#pragma unroll
            for (int j = 0; j < 2; ++j) {
                const int nn = wn + j * 16 + l15;
                bf[j] = *(const short8*)&Bs[cur][nn * 64 + (((kt2 * 4 + quad) ^ (nn & 7)) << 3)];
            }
#pragma unroll
            for (int i = 0; i < 4; ++i)
#pragma unroll
                for (int j = 0; j < 2; ++j)
                    acc[i][j] = __builtin_amdgcn_mfma_f32_16x16x32_bf16(af[i], bf[j], acc[i][j], 0, 0, 0);
        }
        if (more) __syncthreads();
        cur ^= 1;
    }

    // partial K-sum -> atomic accumulate into zero-initialized dyn
#pragma unroll
    for (int i = 0; i < 4; ++i)
#pragma unroll
        for (int j = 0; j < 2; ++j)
#pragma unroll
            for (int r = 0; r < 4; ++r) {
                const int row = row0 + wm + i * 16 + quad * 4 + r;
                const int col = col0 + wn + j * 16 + l15;
                atomicAdd(&C[(size_t)row * N + col], acc[i][j][r]);
            }
}

// ---------------------------------------------------------------------------
extern "C" void kernel_launch(void* const* d_in, const int* in_sizes, int n_in,
                              void* d_out, int out_size, void* d_ws, size_t ws_size,
                              hipStream_t stream) {
    const float* pf = (const float*)d_in[0];   // [B,T,N,C]
    const float* Wh = (const float*)d_in[1];   // [C,C]
    const float* w1 = (const float*)d_in[2];   // [18,C,3,3]
    const float* b1 = (const float*)d_in[3];   // [18]
    const float* w2 = (const float*)d_in[4];
    const float* b2 = (const float*)d_in[5];

    float* dyn = (float*)d_out;                    // [ROWS][C]
    float* mad = dyn + (size_t)ROWS * Cc;          // [ROWS][9][C]

    // workspace layout
    float* off1  = (float*)d_ws;                                  // ROWS*18
    float* off2  = off1 + (size_t)ROWS * 18;                      // ROWS*18
    unsigned short* Ab = (unsigned short*)(off2 + (size_t)ROWS * 18);    // ROWS*C bf16
    unsigned short* Wb = Ab + (size_t)ROWS * Cc;                  // C*C bf16
    _Float16* xh  = (_Float16*)(Wb + (size_t)Cc * Cc);            // ROWS*C fp16
    _Float16* wh1 = xh + (size_t)ROWS * Cc;                       // 9*32*C fp16
    _Float16* wh2 = wh1 + (size_t)9 * 32 * Cc;                    // 9*32*C fp16

    prep_kernel<<<SEG4, 256, 0, stream>>>(pf, Wh, w1, b1, w2, b2,
                                          Wb, xh, wh1, wh2, off1, off2, dyn);
    offs_mfma_kernel<<<dim3(ROWS / 64, 8, 2), 256, 0, stream>>>(xh, wh1, wh2, off1, off2);
    gather_kernel<<<ROWS, 256, 0, stream>>>(pf, off1, off2, Ab, mad);
    gemm_bt_kernel<<<dim3(20, 16, 2), 256, 0, stream>>>(Ab, Wb, dyn, ROWS, Cc, Cc);
}

// Round 7
// 173.314 us; speedup vs baseline: 1.0565x; 1.0565x over previous
//
#include <hip/hip_runtime.h>
#include <hip/hip_bf16.h>

// Problem constants (from setup_inputs)
#define Bb 8
#define Tt 20
#define Nn 16
#define Cc 1024
#define ROWS (Bb * Tt * Nn)   // 2560
#define K2 9

typedef __attribute__((ext_vector_type(8))) short short8;
typedef __attribute__((ext_vector_type(8))) _Float16 half8;
typedef __attribute__((ext_vector_type(4))) _Float16 half4;
typedef __attribute__((ext_vector_type(4))) float floatx4;
typedef __attribute__((address_space(1))) const unsigned int guint;
typedef __attribute__((address_space(3))) unsigned int luint;

static __device__ __forceinline__ unsigned short f2bf(float f) {
    unsigned int u = __builtin_bit_cast(unsigned int, f);
    unsigned int lsb = (u >> 16) & 1u;
    u += 0x7fffu + lsb;                 // round-to-nearest-even
    return (unsigned short)(u >> 16);
}

// ---------------------------------------------------------------------------
// Kernel 0 (prep): one kernel, four block-segments.
//   [0,1024)      : W_hidden fp32 -> bf16 (4 elem/thread)
//   [1024,3584)   : x fp32 -> fp16        (4 elem/thread)
//   [3584,4736)   : conv weights -> [tap][32][C] fp16 (o zero-padded to 32)
//   [4736,4916)   : off1/off2 bias init (offs kernel atomicAdds partials)
// ---------------------------------------------------------------------------
#define SEG0 1024
#define SEG1 3584
#define SEG2 4736
#define SEG3 4916

__global__ __launch_bounds__(256) void prep_kernel(const float* __restrict__ pf,
                                                   const float* __restrict__ Wh,
                                                   const float* __restrict__ w1,
                                                   const float* __restrict__ b1,
                                                   const float* __restrict__ w2,
                                                   const float* __restrict__ b2,
                                                   unsigned short* __restrict__ Wb,
                                                   _Float16* __restrict__ xh,
                                                   _Float16* __restrict__ wh1,
                                                   _Float16* __restrict__ wh2,
                                                   float* __restrict__ off1,
                                                   float* __restrict__ off2) {
    const int bid = blockIdx.x;
    const int tid = threadIdx.x;
    if (bid < SEG0) {
        int idx = (bid * 256 + tid) * 4;
        float4 v = *(const float4*)(Wh + idx);
        ushort4 o;
        o.x = f2bf(v.x); o.y = f2bf(v.y); o.z = f2bf(v.z); o.w = f2bf(v.w);
        *(ushort4*)(Wb + idx) = o;
    } else if (bid < SEG1) {
        int idx = ((bid - SEG0) * 256 + tid) * 4;
        float4 v = *(const float4*)(pf + idx);
        half4 o;
        o.x = (_Float16)v.x; o.y = (_Float16)v.y; o.z = (_Float16)v.z; o.w = (_Float16)v.w;
        *(half4*)(xh + idx) = o;
    } else if (bid < SEG2) {
        int idx = (bid - SEG1) * 256 + tid;     // 9*32*1024 total
        int c = idx & 1023;
        int o = (idx >> 10) & 31;
        int tap = idx >> 15;
        float v1 = 0.f, v2 = 0.f;
        if (o < 18) {
            size_t src = ((size_t)o * Cc + c) * 9 + tap;
            v1 = w1[src]; v2 = w2[src];
        }
        wh1[idx] = (_Float16)v1;
        wh2[idx] = (_Float16)v2;
    } else {
        int idx = (bid - SEG2) * 256 + tid;     // ROWS*18 = 46080 = 180*256
        int o = idx % 18;
        off1[idx] = b1[o];
        off2[idx] = b2[o];
    }
}

// ---------------------------------------------------------------------------
// Kernel 1: offset conv, ALL 9 taps per block, K-SPLIT for parallelism.
// Grid (40 M-tiles of 64 rows, 8 K-chunks of 128, 2 ratios) = 640 blocks
// (R4 measured-best config — byte-identical revert).
// ---------------------------------------------------------------------------
__global__ __launch_bounds__(256) void offs_mfma_kernel(const _Float16* __restrict__ xh,
                                                        const _Float16* __restrict__ wh1,
                                                        const _Float16* __restrict__ wh2,
                                                        float* __restrict__ off1,
                                                        float* __restrict__ off2) {
    __shared__ unsigned short As[2][146 * 32];      // 2 x 9.1 KB (144 win + zero + pad)
    __shared__ unsigned short Bs[2][9 * 32 * 32];   // 2 x 18 KB

    const int tid  = threadIdx.x;
    const int lane = tid & 63;
    const int wave = tid >> 6;
    const int quad = lane >> 4;
    const int l15  = lane & 15;
    const int row0 = blockIdx.x * 64;               // 64 | 320: never crosses a batch
    const int kc   = blockIdx.y * 128;              // this block's K range: [kc, kc+128)
    const int ratio = blockIdx.z + 1;
    const _Float16* __restrict__ wh = blockIdx.z ? wh2 : wh1;
    float* __restrict__ off         = blockIdx.z ? off2 : off1;

    const int wrow = wave * 16;                     // this wave's 16 rows = one t-slice
    const int t_w  = ((row0 + wrow) >> 4) % Tt;

    unsigned bOffs[5], aOffs[3];
#pragma unroll
    for (int i = 0; i < 5; ++i) {
        const int c = (wave + i * 4) * 64 + lane;
        const int tap = c >> 7, rem = c & 127, o = rem >> 2, p = rem & 3;
        bOffs[i] = tap * 32768 + o * 1024 + ((p ^ (o & 3)) << 3);
    }
#pragma unroll
    for (int i = 0; i < 3; ++i) {
        const int c = (wave + i * 4) * 64 + lane;
        const int r = c >> 2, p = c & 3;
        int gr = row0 - 40 + r;                     // clamp for safety; invalid rows
        gr = gr < 0 ? 0 : (gr > ROWS - 1 ? ROWS - 1 : gr);  // are masked by validity
        aOffs[i] = (unsigned)gr * 1024 + ((p ^ (r & 3)) << 3);
    }

    auto stage = [&](int buf, int kt) {
#pragma unroll
        for (int i = 0; i < 5; ++i) {
            const int g = wave + i * 4;
            if (g < 18)
                __builtin_amdgcn_global_load_lds((guint*)(const void*)(wh + bOffs[i] + kt),
                                                 (luint*)(void*)&Bs[buf][g * 512], 16, 0, 0);
        }
#pragma unroll
        for (int i = 0; i < 3; ++i) {
            const int g = wave + i * 4;
            if (g < 9)
                __builtin_amdgcn_global_load_lds((guint*)(const void*)(xh + aOffs[i] + kt),
                                                 (luint*)(void*)&As[buf][g * 512], 16, 0, 0);
        }
    };

    int addrA[9];
#pragma unroll
    for (int tap = 0; tap < 9; ++tap) {
        const int dt = (tap / 3 - 1) * ratio;
        const int dn = (tap % 3 - 1) * ratio;
        const bool tv = (unsigned)(t_w + dt) < (unsigned)Tt;   // wave-uniform
        const bool nv = (unsigned)(l15 + dn) < (unsigned)Nn;   // per-lane
        const int r  = wrow + l15 + 40 + dt * 16 + dn;         // window row
        const int rr = (tv && nv) ? r : 144;                   // else zero row
        addrA[tap] = rr * 32 + ((quad ^ (rr & 3)) << 3);
    }
    const int bOff0 = l15 * 32 + ((quad ^ (l15 & 3)) << 3);

    if (tid < 8) {
        short8 z = {0, 0, 0, 0, 0, 0, 0, 0};
        *(short8*)&As[tid >> 2][144 * 32 + (tid & 3) * 8] = z;
    }

    floatx4 acc[2];
    acc[0] = (floatx4){0.f, 0.f, 0.f, 0.f};
    acc[1] = (floatx4){0.f, 0.f, 0.f, 0.f};

    stage(0, kc);
    __syncthreads();
    int cur = 0;
#pragma unroll
    for (int ks = 0; ks < 4; ++ks) {                // 4 K-steps of 32
        const bool more = (ks < 3);
        if (more) stage(cur ^ 1, kc + (ks + 1) * 32);   // prefetch under the MFMAs
#pragma unroll
        for (int tap = 0; tap < 9; ++tap) {
            const half8 av  = __builtin_bit_cast(half8, *(const short8*)&As[cur][addrA[tap]]);
            const half8 bv0 = __builtin_bit_cast(half8, *(const short8*)&Bs[cur][tap * 1024 + bOff0]);
            const half8 bv1 = __builtin_bit_cast(half8, *(const short8*)&Bs[cur][tap * 1024 + 512 + bOff0]);
            acc[0] = __builtin_amdgcn_mfma_f32_16x16x32_f16(av, bv0, acc[0], 0, 0, 0);
            acc[1] = __builtin_amdgcn_mfma_f32_16x16x32_f16(av, bv1, acc[1], 0, 0, 0);
        }
        if (more) __syncthreads();                  // single drain point per K-step
        cur ^= 1;
    }

#pragma unroll
    for (int j = 0; j < 2; ++j) {
        const int o = j * 16 + l15;
        if (o < 18) {
            const int grow = row0 + wrow + quad * 4;
#pragma unroll
            for (int r = 0; r < 4; ++r)
                atomicAdd(&off[(size_t)(grow + r) * 18 + o], acc[j][r]);
        }
    }
}

// ---------------------------------------------------------------------------
// Kernel 2: fused deformable bilinear gather, descriptor form (R1/R4
// measured-best config — byte-identical revert).
// ---------------------------------------------------------------------------
__global__ __launch_bounds__(256) void gather_kernel(const float* __restrict__ pf,
                                                     const float* __restrict__ off1,
                                                     const float* __restrict__ off2,
                                                     unsigned short* __restrict__ Ab,
                                                     float* __restrict__ mad) {
    const int bid = blockIdx.x;
    const int row = (bid & 7) * (ROWS / 8) + (bid >> 3);   // bijective XCD swizzle
    const int b = row / (Tt * Nn);
    const int t = (row / Nn) % Tt;
    const int n = row % Nn;
    const int tid = threadIdx.x;

    __shared__ float4 scoef[18];
    __shared__ int4   soffs[18];

    if (tid < 18) {
        const int ratio = (tid < 9) ? 1 : 2;
        const int k = (tid < 9) ? tid : tid - 9;
        const float* offarr = (tid < 9) ? off1 : off2;
        const float ot = offarr[(size_t)row * 18 + k];
        const float on = offarr[(size_t)row * 18 + 9 + k];
        const float tmax = (float)(Tt + 2 * ratio - 1);
        const float nmax = (float)(Nn + 2 * ratio - 1);
        const float pos_t = (float)(t + ratio + (k / 3 - 1) * ratio) + ot;
        const float pos_n = (float)(n + ratio + (k % 3 - 1) * ratio) + on;

        const float fl_t = floorf(pos_t), fl_n = floorf(pos_n);
        const float l_t = fminf(fmaxf(fl_t, 0.f), tmax);
        const float r_t = fminf(fmaxf(fl_t + 1.f, 0.f), tmax);
        const float l_n = fminf(fmaxf(fl_n, 0.f), nmax);
        const float r_n = fminf(fmaxf(fl_n + 1.f, 0.f), nmax);
        const float pt_ = fminf(fmaxf(pos_t, 0.f), tmax);
        const float pn_ = fminf(fmaxf(pos_n, 0.f), nmax);

        const float wtl = 1.f - fabsf(pt_ - l_t);
        const float wtr = 1.f - fabsf(pt_ - r_t);
        const float wnl = 1.f - fabsf(pn_ - l_n);
        const float wnr = 1.f - fabsf(pn_ - r_n);

        const int ilt = (int)l_t - ratio, irt = (int)r_t - ratio;
        const int iln = (int)l_n - ratio, irn = (int)r_n - ratio;
        const bool vtl = (unsigned)ilt < (unsigned)Tt;
        const bool vtr = (unsigned)irt < (unsigned)Tt;
        const bool vnl = (unsigned)iln < (unsigned)Nn;
        const bool vnr = (unsigned)irn < (unsigned)Nn;

        const int bb = b * Tt;
        float4 cf;
        int4 of;
        const bool g0 = vtl && vnl, g1 = vtr && vnr, g2 = vtr && vnl, g3 = vtl && vnr;
        cf.x = g0 ? wtl * wnl : 0.f;
        cf.y = g1 ? wtr * wnr : 0.f;
        cf.z = g2 ? wtr * wnl : 0.f;
        cf.w = g3 ? wtl * wnr : 0.f;
        of.x = g0 ? ((bb + ilt) * Nn + iln) * Cc : 0;
        of.y = g1 ? ((bb + irt) * Nn + irn) * Cc : 0;
        of.z = g2 ? ((bb + irt) * Nn + iln) * Cc : 0;
        of.w = g3 ? ((bb + ilt) * Nn + irn) * Cc : 0;
        scoef[tid] = cf;
        soffs[tid] = of;
    }
    __syncthreads();

    const int c4 = tid * 4;
    float ax = 0.f, ay = 0.f, az = 0.f, aw = 0.f;

#pragma unroll
    for (int d = 0; d < 9; ++d) {
        const float4 cf = scoef[d];
        const int4 of = soffs[d];
        const float4 v0 = *(const float4*)(pf + of.x + c4);
        const float4 v1 = *(const float4*)(pf + of.y + c4);
        const float4 v2 = *(const float4*)(pf + of.z + c4);
        const float4 v3 = *(const float4*)(pf + of.w + c4);
        ax += cf.x * v0.x + cf.y * v1.x + cf.z * v2.x + cf.w * v3.x;
        ay += cf.x * v0.y + cf.y * v1.y + cf.z * v2.y + cf.w * v3.y;
        az += cf.x * v0.z + cf.y * v1.z + cf.z * v2.z + cf.w * v3.z;
        aw += cf.x * v0.w + cf.y * v1.w + cf.z * v2.w + cf.w * v3.w;
    }
#pragma unroll
    for (int d = 9; d < 18; ++d) {
        const float4 cf = scoef[d];
        const int4 of = soffs[d];
        const float4 v0 = *(const float4*)(pf + of.x + c4);
        const float4 v1 = *(const float4*)(pf + of.y + c4);
        const float4 v2 = *(const float4*)(pf + of.z + c4);
        const float4 v3 = *(const float4*)(pf + of.w + c4);
        floatx4 val;
        val.x = cf.x * v0.x + cf.y * v1.x + cf.z * v2.x + cf.w * v3.x;
        val.y = cf.x * v0.y + cf.y * v1.y + cf.z * v2.y + cf.w * v3.y;
        val.z = cf.x * v0.z + cf.y * v1.z + cf.z * v2.z + cf.w * v3.z;
        val.w = cf.x * v0.w + cf.y * v1.w + cf.z * v2.w + cf.w * v3.w;
        __builtin_nontemporal_store(val,
            (floatx4*)(mad + ((size_t)row * 9 + (d - 9)) * Cc + c4));
        ax += val.x; ay += val.y; az += val.z; aw += val.w;
    }

    ushort4 o;
    o.x = f2bf(ax * (1.f / 18.f));
    o.y = f2bf(ay * (1.f / 18.f));
    o.z = f2bf(az * (1.f / 18.f));
    o.w = f2bf(aw * (1.f / 18.f));
    *(ushort4*)(Ab + (size_t)row * Cc + c4) = o;
}

// ---------------------------------------------------------------------------
// Kernel 3: bf16 MFMA GEMM  C[M][N] = A[M][K] * B[N][K]^T, 64x64 tiles
// (grid 40x16 = 640 blocks — R4 measured-best config, byte-identical revert).
// 4 waves, each 32x32. BK=64 double-buffered, single barrier per K-step.
// Nontemporal C stores.
// ---------------------------------------------------------------------------
__global__ __launch_bounds__(256) void gemm_bt_kernel(const unsigned short* __restrict__ A,
                                                      const unsigned short* __restrict__ Bw,
                                                      float* __restrict__ C,
                                                      int M, int N, int K) {
    __shared__ unsigned short As[2][64 * 64];   // 2 x 8 KB
    __shared__ unsigned short Bs[2][64 * 64];   // 2 x 8 KB

    const int tid  = threadIdx.x;
    const int lane = tid & 63;
    const int wave = tid >> 6;
    const int quad = lane >> 4;
    const int l15  = lane & 15;
    const int row0 = blockIdx.x * 64;
    const int col0 = blockIdx.y * 64;
    const int wm = (wave >> 1) * 32;
    const int wn = (wave & 1) * 32;

    floatx4 acc[2][2];
#pragma unroll
    for (int i = 0; i < 2; ++i)
#pragma unroll
        for (int j = 0; j < 2; ++j) acc[i][j] = (floatx4){0.f, 0.f, 0.f, 0.f};

    const int p  = tid & 7;
    const int m0 = tid >> 3;
    const int m1 = m0 + 32;
    const int kq0 = p ^ (m0 & 7);
    const int kq1 = p ^ (m1 & 7);

    const unsigned short* gA0 = A  + (size_t)(row0 + m0) * K + kq0 * 8;
    const unsigned short* gA1 = A  + (size_t)(row0 + m1) * K + kq1 * 8;
    const unsigned short* gB0 = Bw + (size_t)(col0 + m0) * K + kq0 * 8;
    const unsigned short* gB1 = Bw + (size_t)(col0 + m1) * K + kq1 * 8;

    auto stage = [&](int buf, int kt) {
        unsigned short* a  = &As[buf][0] + wave * 512;
        unsigned short* bb = &Bs[buf][0] + wave * 512;
        __builtin_amdgcn_global_load_lds((guint*)(const void*)(gA0 + kt),
                                         (luint*)(void*)a, 16, 0, 0);
        __builtin_amdgcn_global_load_lds((guint*)(const void*)(gA1 + kt),
                                         (luint*)(void*)(a + 2048), 16, 0, 0);
        __builtin_amdgcn_global_load_lds((guint*)(const void*)(gB0 + kt),
                                         (luint*)(void*)bb, 16, 0, 0);
        __builtin_amdgcn_global_load_lds((guint*)(const void*)(gB1 + kt),
                                         (luint*)(void*)(bb + 2048), 16, 0, 0);
    };

    stage(0, 0);
    __syncthreads();
    int cur = 0;
    for (int kt = 0; kt < K; kt += 64) {
        const bool more = (kt + 64 < K);
        if (more) stage(cur ^ 1, kt + 64);   // prefetch under the MFMAs

#pragma unroll
        for (int kt2 = 0; kt2 < 2; ++kt2) {
            short8 af[2], bf[2];
#pragma unroll
            for (int i = 0; i < 2; ++i) {
                const int mm = wm + i * 16 + l15;
                af[i] = *(const short8*)&As[cur][mm * 64 + (((kt2 * 4 + quad) ^ (mm & 7)) << 3)];
                const int nn = wn + i * 16 + l15;
                bf[i] = *(const short8*)&Bs[cur][nn * 64 + (((kt2 * 4 + quad) ^ (nn & 7)) << 3)];
            }
#pragma unroll
            for (int i = 0; i < 2; ++i)
#pragma unroll
                for (int j = 0; j < 2; ++j)
                    acc[i][j] = __builtin_amdgcn_mfma_f32_16x16x32_bf16(af[i], bf[j], acc[i][j], 0, 0, 0);
        }
        if (more) __syncthreads();
        cur ^= 1;
    }

#pragma unroll
    for (int i = 0; i < 2; ++i)
#pragma unroll
        for (int j = 0; j < 2; ++j)
#pragma unroll
            for (int r = 0; r < 4; ++r) {
                const int row = row0 + wm + i * 16 + quad * 4 + r;
                const int col = col0 + wn + j * 16 + l15;
                __builtin_nontemporal_store(acc[i][j][r], &C[(size_t)row * N + col]);
            }
}

// ---------------------------------------------------------------------------
extern "C" void kernel_launch(void* const* d_in, const int* in_sizes, int n_in,
                              void* d_out, int out_size, void* d_ws, size_t ws_size,
                              hipStream_t stream) {
    const float* pf = (const float*)d_in[0];   // [B,T,N,C]
    const float* Wh = (const float*)d_in[1];   // [C,C]
    const float* w1 = (const float*)d_in[2];   // [18,C,3,3]
    const float* b1 = (const float*)d_in[3];   // [18]
    const float* w2 = (const float*)d_in[4];
    const float* b2 = (const float*)d_in[5];

    float* dyn = (float*)d_out;                    // [ROWS][C]
    float* mad = dyn + (size_t)ROWS * Cc;          // [ROWS][9][C]

    // workspace layout
    float* off1  = (float*)d_ws;                                  // ROWS*18
    float* off2  = off1 + (size_t)ROWS * 18;                      // ROWS*18
    unsigned short* Ab = (unsigned short*)(off2 + (size_t)ROWS * 18);    // ROWS*C bf16
    unsigned short* Wb = Ab + (size_t)ROWS * Cc;                  // C*C bf16
    _Float16* xh  = (_Float16*)(Wb + (size_t)Cc * Cc);            // ROWS*C fp16
    _Float16* wh1 = xh + (size_t)ROWS * Cc;                       // 9*32*C fp16
    _Float16* wh2 = wh1 + (size_t)9 * 32 * Cc;                    // 9*32*C fp16

    prep_kernel<<<SEG3, 256, 0, stream>>>(pf, Wh, w1, b1, w2, b2,
                                          Wb, xh, wh1, wh2, off1, off2);
    offs_mfma_kernel<<<dim3(ROWS / 64, 8, 2), 256, 0, stream>>>(xh, wh1, wh2, off1, off2);
    gather_kernel<<<ROWS, 256, 0, stream>>>(pf, off1, off2, Ab, mad);
    gemm_bt_kernel<<<dim3(40, 16), 256, 0, stream>>>(Ab, Wb, dyn, ROWS, Cc, Cc);
}